// Round 4
// baseline (282.584 us; speedup 1.0000x reference)
//
#include <hip/hip_runtime.h>

// Problem constants (from reference setup_inputs) — all tensors are float32.
#define B_DIM 2
#define C_DIM 64
#define N_DIM 1024
#define E_DIM 32
#define BE_DIM (B_DIM * E_DIM)   // 64
#define ROWS_PER_BLOCK 16        // rows of the NxN output per block

// Native clang vector type — required by __builtin_nontemporal_store
// (HIP's float4 is a class and is rejected by the builtin).
typedef float vfloat4 __attribute__((ext_vector_type(4)));

// ---------------------------------------------------------------------------
// Kernel 1: t[b,e,n] = sum_c th12[e,c] * emb[b,c,n], for both parameter sets.
// Grid: (N/256, BE), block 256. ~17 MFLOP total — negligible.
// ---------------------------------------------------------------------------
__global__ __launch_bounds__(256) void compute_t_kernel(
    const float* __restrict__ emb,
    const float* __restrict__ th12_1,
    const float* __restrict__ th12_2,
    float* __restrict__ t1,
    float* __restrict__ t2)
{
    const int n  = blockIdx.x * 256 + threadIdx.x;
    const int be = blockIdx.y;
    const int b  = be >> 5;       // E=32
    const int e  = be & 31;

    const float* __restrict__ embp = emb + (size_t)b * C_DIM * N_DIM + n;
    const float* __restrict__ w1   = th12_1 + e * C_DIM;
    const float* __restrict__ w2   = th12_2 + e * C_DIM;

    float acc1 = 0.f, acc2 = 0.f;
#pragma unroll
    for (int c = 0; c < C_DIM; ++c) {
        const float x = embp[(size_t)c * N_DIM];
        acc1 = fmaf(w1[c], x, acc1);
        acc2 = fmaf(w2[c], x, acc2);
    }
    t1[be * N_DIM + n] = acc1;
    t2[be * N_DIM + n] = acc2;
}

// ---------------------------------------------------------------------------
// Kernel 2: out[b,e,i,j] = relu(2*max(t1i,t1j) + th5_1[e]*(i==j))
//                        * sigmoid(relu(2*max(t2i,t2j) + th5_2[e]*(i==j)))
// Grid: (N/ROWS_PER_BLOCK, BE), block 256.
// Each thread owns 4 consecutive j (held in registers) and loops over 16
// rows i -> j-column values are read from L2 ONCE per 16 rows (16x less
// read traffic than one-row-per-block). Output stored nontemporally
// (16 B/lane coalesced) so the 256 MiB write stream doesn't evict the t
// arrays from L2.
// ---------------------------------------------------------------------------
__global__ __launch_bounds__(256) void edge_kernel(
    const float* __restrict__ t1,
    const float* __restrict__ t2,
    const float* __restrict__ th5_1,
    const float* __restrict__ th5_2,
    float* __restrict__ out)
{
    const int be = blockIdx.y;
    const int e  = be & 31;
    const int i0 = blockIdx.x * ROWS_PER_BLOCK;
    const int jb = threadIdx.x * 4;

    const float* __restrict__ t1r = t1 + be * N_DIM;
    const float* __restrict__ t2r = t2 + be * N_DIM;

    const float th51 = th5_1[e];
    const float th52 = th5_2[e];

    // Per-thread column values: loaded once, reused for all 16 rows.
    const vfloat4 v1 = *reinterpret_cast<const vfloat4*>(t1r + jb);
    const vfloat4 v2 = *reinterpret_cast<const vfloat4*>(t2r + jb);

    float* dst = out + ((size_t)be * N_DIM + i0) * N_DIM + jb;

#pragma unroll
    for (int r = 0; r < ROWS_PER_BLOCK; ++r) {
        const int i = i0 + r;
        const float t1i = t1r[i];   // block-uniform -> scalar load
        const float t2i = t2r[i];

        vfloat4 o;
#pragma unroll
        for (int k = 0; k < 4; ++k) {
            float d1 = 2.f * fmaxf(t1i, v1[k]);
            float d2 = 2.f * fmaxf(t2i, v2[k]);
            if (i == jb + k) { d1 += th51; d2 += th52; }   // diagonal term
            const float adj  = fmaxf(d1, 0.f);
            const float rg   = fmaxf(d2, 0.f);
            // fast sigmoid: v_exp_f32 + v_rcp_f32 (error ~1e-6, slack 0.125)
            const float gate = __builtin_amdgcn_rcpf(1.f + __expf(-rg));
            o[k] = adj * gate;
        }
        __builtin_nontemporal_store(o, reinterpret_cast<vfloat4*>(dst + (size_t)r * N_DIM));
    }
}

// ---------------------------------------------------------------------------
extern "C" void kernel_launch(void* const* d_in, const int* in_sizes, int n_in,
                              void* d_out, int out_size, void* d_ws, size_t ws_size,
                              hipStream_t stream) {
    const float* emb    = (const float*)d_in[0];
    const float* th12_1 = (const float*)d_in[1];
    // d_in[2] = th34_1 (unused by reference)
    const float* th5_1  = (const float*)d_in[3];
    const float* th12_2 = (const float*)d_in[4];
    // d_in[5] = th34_2 (unused by reference)
    const float* th5_2  = (const float*)d_in[6];
    float* out = (float*)d_out;

    float* t1 = (float*)d_ws;                       // BE*N floats = 256 KB
    float* t2 = t1 + (size_t)BE_DIM * N_DIM;        // another 256 KB

    dim3 g1(N_DIM / 256, BE_DIM);
    compute_t_kernel<<<g1, 256, 0, stream>>>(emb, th12_1, th12_2, t1, t2);

    dim3 g2(N_DIM / ROWS_PER_BLOCK, BE_DIM);
    edge_kernel<<<g2, 256, 0, stream>>>(t1, t2, th5_1, th5_2, out);
}

// Round 5
// 269.889 us; speedup vs baseline: 1.0470x; 1.0470x over previous
//
#include <hip/hip_runtime.h>

// Problem constants (from reference setup_inputs) — all tensors are float32.
#define B_DIM 2
#define C_DIM 64
#define N_DIM 1024
#define E_DIM 32
#define BE_DIM (B_DIM * E_DIM)   // 64
#define ROWS_PER_BLOCK 16        // rows of the NxN output per block

typedef float vfloat4 __attribute__((ext_vector_type(4)));

// ---------------------------------------------------------------------------
// Kernel 1: T[b,e,n] = 2 * sum_c th12[e,c] * emb[b,c,n]  (pre-doubled!)
// for both parameter sets. Grid: (N/256, BE), block 256. ~17 MFLOP.
// ---------------------------------------------------------------------------
__global__ __launch_bounds__(256) void compute_t_kernel(
    const float* __restrict__ emb,
    const float* __restrict__ th12_1,
    const float* __restrict__ th12_2,
    float* __restrict__ t1,
    float* __restrict__ t2)
{
    const int n  = blockIdx.x * 256 + threadIdx.x;
    const int be = blockIdx.y;
    const int b  = be >> 5;       // E=32
    const int e  = be & 31;

    const float* __restrict__ embp = emb + (size_t)b * C_DIM * N_DIM + n;
    const float* __restrict__ w1   = th12_1 + e * C_DIM;
    const float* __restrict__ w2   = th12_2 + e * C_DIM;

    float acc1 = 0.f, acc2 = 0.f;
#pragma unroll
    for (int c = 0; c < C_DIM; ++c) {
        const float x = embp[(size_t)c * N_DIM];
        acc1 = fmaf(w1[c], x, acc1);
        acc2 = fmaf(w2[c], x, acc2);
    }
    t1[be * N_DIM + n] = 2.f * acc1;   // pre-doubled: edge kernel needs 2*max(ti,tj)
    t2[be * N_DIM + n] = 2.f * acc2;   //   = max(2ti, 2tj)
}

// ---------------------------------------------------------------------------
// Kernel 2: out[b,e,i,j] = relu(max(T1i,T1j) + th5_1[e]*(i==j))
//                        * sigmoid(relu(max(T2i,T2j) + th5_2[e]*(i==j)))
// where T = 2t. Grid: (N/ROWS_PER_BLOCK, BE), block 256.
// Each thread owns 4 consecutive j (registers), loops over 16 rows i.
// Reads: 2 rows x 4KB per block from L2 (32 MB total — trivial).
// Writes: each block stores a fully contiguous 64 KB region, 16 B/lane
// coalesced dwordx4, REGULAR stores (same path as the 6.3 TB/s fill).
// ---------------------------------------------------------------------------
__global__ __launch_bounds__(256) void edge_kernel(
    const float* __restrict__ t1,
    const float* __restrict__ t2,
    const float* __restrict__ th5_1,
    const float* __restrict__ th5_2,
    float* __restrict__ out)
{
    const int be = blockIdx.y;
    const int e  = be & 31;
    const int i0 = blockIdx.x * ROWS_PER_BLOCK;
    const int jb = threadIdx.x * 4;

    const float* __restrict__ t1r = t1 + be * N_DIM;
    const float* __restrict__ t2r = t2 + be * N_DIM;

    const float th51 = th5_1[e];
    const float th52 = th5_2[e];

    // Per-thread column values: loaded once, reused for all 16 rows.
    const vfloat4 v1 = *reinterpret_cast<const vfloat4*>(t1r + jb);
    const vfloat4 v2 = *reinterpret_cast<const vfloat4*>(t2r + jb);

    float* dst = out + ((size_t)be * N_DIM + i0) * N_DIM + jb;

#pragma unroll
    for (int r = 0; r < ROWS_PER_BLOCK; ++r) {
        const int i = i0 + r;
        const float t1i = t1r[i];   // block-uniform broadcast load
        const float t2i = t2r[i];

        vfloat4 o;
#pragma unroll
        for (int k = 0; k < 4; ++k) {
            float d1 = fmaxf(t1i, v1[k]);
            float d2 = fmaxf(t2i, v2[k]);
            if (i == jb + k) { d1 += th51; d2 += th52; }   // diagonal term
            const float adj  = fmaxf(d1, 0.f);
            const float rg   = fmaxf(d2, 0.f);
            // fast sigmoid: v_exp_f32 + v_rcp_f32 (error ~1e-6, slack 0.125)
            const float gate = __builtin_amdgcn_rcpf(1.f + __expf(-rg));
            o[k] = adj * gate;
        }
        *reinterpret_cast<vfloat4*>(dst + (size_t)r * N_DIM) = o;
    }
}

// ---------------------------------------------------------------------------
extern "C" void kernel_launch(void* const* d_in, const int* in_sizes, int n_in,
                              void* d_out, int out_size, void* d_ws, size_t ws_size,
                              hipStream_t stream) {
    const float* emb    = (const float*)d_in[0];
    const float* th12_1 = (const float*)d_in[1];
    // d_in[2] = th34_1 (unused by reference)
    const float* th5_1  = (const float*)d_in[3];
    const float* th12_2 = (const float*)d_in[4];
    // d_in[5] = th34_2 (unused by reference)
    const float* th5_2  = (const float*)d_in[6];
    float* out = (float*)d_out;

    float* t1 = (float*)d_ws;                       // BE*N floats = 256 KB
    float* t2 = t1 + (size_t)BE_DIM * N_DIM;        // another 256 KB

    dim3 g1(N_DIM / 256, BE_DIM);
    compute_t_kernel<<<g1, 256, 0, stream>>>(emb, th12_1, th12_2, t1, t2);

    dim3 g2(N_DIM / ROWS_PER_BLOCK, BE_DIM);
    edge_kernel<<<g2, 256, 0, stream>>>(t1, t2, th5_1, th5_2, out);
}